// Round 1
// baseline (616.743 us; speedup 1.0000x reference)
//
#include <hip/hip_runtime.h>
#include <hip/hip_bf16.h>

// Problem constants
#define BB 4
#define CC 128
#define RN 4096
#define KK 16
#define NROWS (BB*RN*KK)   // 262144
#define EPSV 1e-5f

// ---------------- workspace layout (float indices) ----------------
// [0, 16384)        bn2 slots: 64 slots x 128 ch x {sum, sumsq}
// [16384, 17152)    stat slots: 64 slots x 12  (Sx,Sy,Sz,Mxx,Mxy,Mxz,Myy,Myz,Mzz,pad)
// [17152, 17568)    params: scale1[64] shift1[64] scalew[16] shiftw[16] scale2[128] shift2[128]
// [18432, 83968)    qpack: 16384 x float4 (x,y,z,sq)
// [83968, 346112)   idx: 262144 int
// [346112, 608256)  zw_raw: 262144 f32
// [608256, 2705408) f_t: (B,N,C) transposed features
// [2705408, ...)    z2: 262144 x 128 bf16  (67.1 MB)

__global__ void k_prep(const float* __restrict__ Q, float4* __restrict__ qp) {
    int gid = blockIdx.x * 256 + threadIdx.x;
    if (gid < BB * RN) {
        int b = gid >> 12, n = gid & (RN - 1);
        size_t base = (size_t)b * 3 * RN;
        float x = Q[base + n], y = Q[base + RN + n], z = Q[base + 2 * RN + n];
        qp[gid] = make_float4(x, y, z, fmaf(x, x, fmaf(y, y, z * z)));
    }
}

__global__ void k_transpose(const float* __restrict__ FE, float* __restrict__ ft) {
    __shared__ float t[32][33];
    int bid = blockIdx.x;
    int b = bid >> 9;            // 512 blocks per batch
    int cb = (bid >> 7) & 3;
    int nb = bid & 127;
    int c0 = cb * 32, n0 = nb * 32;
    int tid = threadIdx.x;
    for (int o = tid; o < 1024; o += 256) {
        int i = o >> 5, j = o & 31;
        t[i][j] = FE[((size_t)b * CC + c0 + i) * RN + n0 + j];
    }
    __syncthreads();
    for (int o = tid; o < 1024; o += 256) {
        int j = o >> 5, i = o & 31;
        ft[((size_t)b * RN + n0 + j) * CC + c0 + i] = t[i][j];
    }
}

// One wave per query row. Distributed sorted top-16: lane k holds k-th smallest (d2,idx).
__global__ __launch_bounds__(256) void k_knn(const float4* __restrict__ qp, int* __restrict__ idxout,
                                             float* __restrict__ zwout, float* __restrict__ statslots,
                                             const float* __restrict__ Ww, const float* __restrict__ bw) {
    __shared__ float4 tile[256];
    __shared__ float bacc[9];
    const int tid = threadIdx.x;
    if (tid < 9) bacc[tid] = 0.f;
    const int lane = tid & 63;
    const int wid = tid >> 6;
    const int row = blockIdx.x * 4 + wid;          // all 4 rows of a block share b
    const int b = row >> 12, n = row & (RN - 1);
    const float4* qb = qp + b * RN;
    const float4 self = qb[n];
    float ld = 3.4e38f; int li = 0x7FFFFFFF;       // lane's list element
    float g15d = 3.4e38f; int g15i = 0x7FFFFFFF;   // running 16th (wave-uniform)

    for (int t0 = 0; t0 < RN; t0 += 256) {
        __syncthreads();
        tile[tid] = qb[t0 + tid];
        __syncthreads();
        for (int s = 0; s < 256; s += 64) {
            const int m = t0 + s + lane;
            float4 cp = tile[s + lane];
            float d2 = self.w + cp.w - 2.f * fmaf(self.x, cp.x, fmaf(self.y, cp.y, self.z * cp.z));
            bool beats = (d2 < g15d) || (d2 == g15d && m < g15i);
            unsigned long long mask = __ballot(beats);
            while (mask) {
                int src = (int)__builtin_ctzll(mask);
                mask &= mask - 1;
                float cd = __shfl(d2, src);
                int   ci = __shfl(m, src);
                bool lt2 = (ld < cd) || (ld == cd && li < ci);
                int p = (int)__builtin_popcountll(__ballot(lt2) & 0xFFFFull);
                float sd = __shfl_up(ld, 1);
                int   si = __shfl_up(li, 1);
                if (lane == p)      { ld = cd; li = ci; }
                else if (lane > p)  { ld = sd; li = si; }
            }
            g15d = __shfl(ld, 15); g15i = __shfl(li, 15);
        }
    }

    // post: lanes 0..15 hold neighbors in exact top_k order
    float sx = 0.f, sy = 0.f, sz = 0.f;
    if (lane < 16) {
        idxout[row * 16 + lane] = li;
        float4 pn = qb[li];
        sx = pn.x - self.x; sy = pn.y - self.y; sz = pn.z - self.z;
        float zw = fmaf(Ww[lane * 3], sx, fmaf(Ww[lane * 3 + 1], sy, fmaf(Ww[lane * 3 + 2], sz, bw[lane])));
        zwout[row * 16 + lane] = zw;
    }
    float vals[9] = {sx, sy, sz, sx * sx, sx * sy, sx * sz, sy * sy, sy * sz, sz * sz};
    #pragma unroll
    for (int i = 0; i < 9; ++i) {
        float v = vals[i];
        for (int off = 32; off; off >>= 1) v += __shfl_down(v, off);
        if (lane == 0) atomicAdd(&bacc[i], v);
    }
    __syncthreads();
    if (tid < 9) atomicAdd(&statslots[(blockIdx.x & 63) * 12 + tid], bacc[tid]);
}

// Analytic BN1 / BNw stats from the 12 moments.
__global__ void k_bn1(const float* __restrict__ slots, const float* __restrict__ W1, const float* __restrict__ b1,
                      const float* __restrict__ g1, const float* __restrict__ be1,
                      const float* __restrict__ Ww, const float* __restrict__ bw,
                      const float* __restrict__ gw, const float* __restrict__ bew, float* __restrict__ par) {
    __shared__ float st[12];
    int tid = threadIdx.x;
    if (tid < 12) {
        float s = 0.f;
        for (int i = 0; i < 64; ++i) s += slots[i * 12 + tid];
        st[tid] = s;
    }
    __syncthreads();
    const float invN = 1.0f / (float)NROWS;
    float mx = st[0] * invN, my = st[1] * invN, mz = st[2] * invN;
    float Cxx = st[3] * invN - mx * mx, Cxy = st[4] * invN - mx * my, Cxz = st[5] * invN - mx * mz;
    float Cyy = st[6] * invN - my * my, Cyz = st[7] * invN - my * mz, Czz = st[8] * invN - mz * mz;
    if (tid < 64) {
        float w0 = W1[tid * 3], w1 = W1[tid * 3 + 1], w2 = W1[tid * 3 + 2];
        float mean = w0 * mx + w1 * my + w2 * mz + b1[tid];
        float var = w0 * w0 * Cxx + w1 * w1 * Cyy + w2 * w2 * Czz
                  + 2.f * (w0 * w1 * Cxy + w0 * w2 * Cxz + w1 * w2 * Cyz);
        float sc = g1[tid] * rsqrtf(var + EPSV);
        par[tid] = sc;
        par[64 + tid] = be1[tid] - mean * sc;
    } else if (tid < 80) {
        int k = tid - 64;
        float w0 = Ww[k * 3], w1 = Ww[k * 3 + 1], w2 = Ww[k * 3 + 2];
        float mean = w0 * mx + w1 * my + w2 * mz + bw[k];
        float var = w0 * w0 * Cxx + w1 * w1 * Cyy + w2 * w2 * Czz
                  + 2.f * (w0 * w1 * Cxy + w0 * w2 * Cxz + w1 * w2 * Cyz);
        float sc = gw[k] * rsqrtf(var + EPSV);
        par[128 + k] = sc;
        par[144 + k] = bew[k] - mean * sc;
    }
}

// Fused: build concat tile (gather + enc_sub) in LDS, fp32 GEMM vs W2, write z2 (bf16) + BN2 partial stats.
__global__ __launch_bounds__(256) void k_main(const float* __restrict__ ft, const int* __restrict__ idxb,
                                              const float4* __restrict__ qp, const float* __restrict__ W1,
                                              const float* __restrict__ b1, const float* __restrict__ W2,
                                              const float* __restrict__ b2, const float* __restrict__ par,
                                              float* __restrict__ bn2slots, __hip_bfloat16* __restrict__ z2) {
    __shared__ float A[64][192];
    __shared__ union { float bt[24][136]; float red[2048]; } u;
    __shared__ float subs[64][3];
    __shared__ int nbr[64];
    const int tid = threadIdx.x;
    const int bid = blockIdx.x;
    const int pair0 = bid * 4;            // 4 (b,r) pairs per block -> 64 rows
    const int b = pair0 >> 12;

    if (tid < 64) {
        int g = tid >> 4, k = tid & 15;
        int pair = pair0 + g;
        int n = idxb[pair * 16 + k];
        nbr[tid] = n;
        float4 pn = qp[b * RN + n];
        float4 ps = qp[pair];
        subs[tid][0] = pn.x - ps.x;
        subs[tid][1] = pn.y - ps.y;
        subs[tid][2] = pn.z - ps.z;
    }
    __syncthreads();
    // enc_sub -> A[:, 128:192]
    for (int o = tid; o < 64 * 64; o += 256) {
        int rl = o >> 6, c = o & 63;
        float z = fmaf(W1[c * 3], subs[rl][0],
                  fmaf(W1[c * 3 + 1], subs[rl][1],
                  fmaf(W1[c * 3 + 2], subs[rl][2], b1[c])));
        float e = fmaf(z, par[c], par[64 + c]);
        A[rl][128 + c] = fmaxf(e, 0.f);
    }
    // grouped_F -> A[:, 0:128]   (contiguous 512B gathers from transposed features)
    for (int o = tid; o < 64 * 128; o += 256) {
        int rl = o >> 7, c = o & 127;
        A[rl][c] = ft[((size_t)(b * RN + nbr[rl])) * CC + c];
    }
    __syncthreads();

    const int cgrp = tid & 31, rgrp = tid >> 5;
    const int c0 = cgrp * 4, r0l = rgrp * 8;
    float acc[8][4];
    #pragma unroll
    for (int rr = 0; rr < 8; ++rr) {
        acc[rr][0] = b2[c0]; acc[rr][1] = b2[c0 + 1]; acc[rr][2] = b2[c0 + 2]; acc[rr][3] = b2[c0 + 3];
    }
    for (int jt = 0; jt < 8; ++jt) {
        for (int o = tid; o < 24 * 128; o += 256) {
            int cc = o / 24, jj = o - cc * 24;
            u.bt[jj][cc] = W2[cc * 192 + jt * 24 + jj];
        }
        __syncthreads();
        #pragma unroll 4
        for (int j = 0; j < 24; ++j) {
            float4 bv = *(const float4*)&u.bt[j][c0];
            float av[8];
            #pragma unroll
            for (int rr = 0; rr < 8; ++rr) av[rr] = A[r0l + rr][jt * 24 + j];
            #pragma unroll
            for (int rr = 0; rr < 8; ++rr) {
                acc[rr][0] = fmaf(av[rr], bv.x, acc[rr][0]);
                acc[rr][1] = fmaf(av[rr], bv.y, acc[rr][1]);
                acc[rr][2] = fmaf(av[rr], bv.z, acc[rr][2]);
                acc[rr][3] = fmaf(av[rr], bv.w, acc[rr][3]);
            }
        }
        __syncthreads();
    }
    // BN2 partial stats (pre-bf16-rounding, fp32)
    #pragma unroll
    for (int cc = 0; cc < 4; ++cc) {
        float s = 0.f, s2 = 0.f;
        #pragma unroll
        for (int rr = 0; rr < 8; ++rr) { float v = acc[rr][cc]; s += v; s2 = fmaf(v, v, s2); }
        u.red[rgrp * 256 + (c0 + cc) * 2] = s;
        u.red[rgrp * 256 + (c0 + cc) * 2 + 1] = s2;
    }
    __syncthreads();
    {
        float v = 0.f;
        #pragma unroll
        for (int r = 0; r < 8; ++r) v += u.red[r * 256 + tid];
        atomicAdd(&bn2slots[(bid & 63) * 256 + tid], v);
    }
    // z2 store (bf16, 8B per row-slice)
    #pragma unroll
    for (int rr = 0; rr < 8; ++rr) {
        size_t row = (size_t)pair0 * 16 + r0l + rr;
        union { __hip_bfloat16 h[4]; uint2 u2; } pk;
        pk.h[0] = __float2bfloat16(acc[rr][0]);
        pk.h[1] = __float2bfloat16(acc[rr][1]);
        pk.h[2] = __float2bfloat16(acc[rr][2]);
        pk.h[3] = __float2bfloat16(acc[rr][3]);
        *(uint2*)(z2 + row * CC + c0) = pk.u2;
    }
}

__global__ void k_bn2(const float* __restrict__ slots, const float* __restrict__ g2,
                      const float* __restrict__ be2, float* __restrict__ par) {
    __shared__ float red[256];
    int tid = threadIdx.x;
    float v = 0.f;
    for (int s = 0; s < 64; ++s) v += slots[s * 256 + tid];
    red[tid] = v;
    __syncthreads();
    if (tid < 128) {
        const float invN = 1.0f / (float)NROWS;
        float mean = red[2 * tid] * invN;
        float var = red[2 * tid + 1] * invN - mean * mean;
        float sc = g2[tid] * rsqrtf(var + EPSV);
        par[160 + tid] = sc;
        par[288 + tid] = be2[tid] - mean * sc;
    }
}

// Epilogue: BN2+ReLU, weight by w_diag, sum over K, residual, transpose to (B,C,N).
__global__ __launch_bounds__(256) void k_out(const __hip_bfloat16* __restrict__ z2, const float* __restrict__ zw_raw,
                                             const float* __restrict__ par, const float* __restrict__ F_E,
                                             float* __restrict__ out) {
    __shared__ float wd[32][16];
    __shared__ float outs[32][129];
    const int tid = threadIdx.x;
    const int b = blockIdx.x >> 7;
    const int r0 = (blockIdx.x & 127) * 32;
    const int rowbase = (b * RN + r0) * 16;
    for (int o = tid; o < 512; o += 256) {
        int rr = o >> 4, k = o & 15;
        wd[rr][k] = fmaxf(fmaf(zw_raw[rowbase + o], par[128 + k], par[144 + k]), 0.f);
    }
    __syncthreads();
    const int c0 = (tid & 63) * 2;
    const int rh = tid >> 6;
    const float sc0 = par[160 + c0], sh0 = par[288 + c0];
    const float sc1 = par[160 + c0 + 1], sh1 = par[288 + c0 + 1];
    for (int rr = rh; rr < 32; rr += 4) {
        float a0 = 0.f, a1 = 0.f;
        const __hip_bfloat16* zp = z2 + ((size_t)rowbase + rr * 16) * CC + c0;
        #pragma unroll
        for (int k = 0; k < 16; ++k) {
            unsigned int uu = *(const unsigned int*)(zp + k * CC);
            float z0 = __uint_as_float(uu << 16);
            float z1 = __uint_as_float(uu & 0xFFFF0000u);
            float w = wd[rr][k];
            a0 += fmaxf(fmaf(z0, sc0, sh0), 0.f) * w;
            a1 += fmaxf(fmaf(z1, sc1, sh1), 0.f) * w;
        }
        outs[rr][c0] = a0; outs[rr][c0 + 1] = a1;
    }
    __syncthreads();
    for (int o = tid; o < 4096; o += 256) {
        int c = o >> 5, rr = o & 31;
        size_t oi = ((size_t)b * CC + c) * RN + r0 + rr;
        out[oi] = outs[rr][c] + F_E[oi];
    }
}

extern "C" void kernel_launch(void* const* d_in, const int* in_sizes, int n_in,
                              void* d_out, int out_size, void* d_ws, size_t ws_size,
                              hipStream_t stream) {
    const float* F_E = (const float*)d_in[0];
    const float* Qp  = (const float*)d_in[1];
    const float* W1  = (const float*)d_in[2];
    const float* b1  = (const float*)d_in[3];
    const float* g1  = (const float*)d_in[4];
    const float* be1 = (const float*)d_in[5];
    const float* W2  = (const float*)d_in[6];
    const float* b2  = (const float*)d_in[7];
    const float* g2  = (const float*)d_in[8];
    const float* be2 = (const float*)d_in[9];
    const float* Ww  = (const float*)d_in[10];
    const float* bw  = (const float*)d_in[11];
    const float* gw  = (const float*)d_in[12];
    const float* bew = (const float*)d_in[13];
    float* out = (float*)d_out;
    float* wsf = (float*)d_ws;

    float* bn2slots   = wsf;
    float* statslots  = wsf + 16384;
    float* par        = wsf + 17152;
    float4* qpack     = (float4*)(wsf + 18432);
    int* idxb         = (int*)(wsf + 83968);
    float* zw_raw     = wsf + 346112;
    float* f_t        = wsf + 608256;
    __hip_bfloat16* z2 = (__hip_bfloat16*)(wsf + 2705408);

    hipMemsetAsync(d_ws, 0, 17152 * sizeof(float), stream);   // zero accumulators only
    k_prep<<<64, 256, 0, stream>>>(Qp, qpack);
    k_transpose<<<2048, 256, 0, stream>>>(F_E, f_t);
    k_knn<<<4096, 256, 0, stream>>>(qpack, idxb, zw_raw, statslots, Ww, bw);
    k_bn1<<<1, 128, 0, stream>>>(statslots, W1, b1, g1, be1, Ww, bw, gw, bew, par);
    k_main<<<4096, 256, 0, stream>>>(f_t, idxb, qpack, W1, b1, W2, b2, par, bn2slots, z2);
    k_bn2<<<1, 256, 0, stream>>>(bn2slots, g2, be2, par);
    k_out<<<512, 256, 0, stream>>>(z2, zw_raw, par, F_E, out);
}

// Round 2
// 330.855 us; speedup vs baseline: 1.8641x; 1.8641x over previous
//
#include <hip/hip_runtime.h>
#include <hip/hip_bf16.h>

// Problem constants
#define BB 4
#define CC 128
#define RN 4096
#define KK 16
#define NROWS (BB*RN*KK)   // 262144
#define EPSV 1e-5f

typedef __attribute__((ext_vector_type(8))) short short8;
typedef __attribute__((ext_vector_type(4))) float f32x4;

__device__ inline ushort f2bf(float f) {
    union { __hip_bfloat16 h; ushort u; } cv;
    cv.h = __float2bfloat16(f);
    return cv.u;
}

// ---------------- workspace layout (float indices) ----------------
// [0, 16384)          bn2 slots: 64 slots x 128 ch x {sum, sumsq}
// [16384, 17152)      stat slots: 64 slots x 12
// [17152, 17568)      params: scale1[64] shift1[64] scalew[16] shiftw[16] scale2[128] shift2[128]
// [17664, 29952)      W2 bf16 (128x192 ushort)
// [32768, 98304)      qpack: 16384 x float4
// [98304, 360448)     idx: 262144 int
// [360448, 622592)    zw_raw: 262144 f32
// [622592, 1671168)   ft bf16: (B,N,128) ushort
// [1671168, ...)      z2: 262144 x 128 bf16 (67.1 MB)

__global__ void k_prep(const float* __restrict__ Q, float4* __restrict__ qp) {
    int gid = blockIdx.x * 256 + threadIdx.x;
    if (gid < BB * RN) {
        int b = gid >> 12, n = gid & (RN - 1);
        size_t base = (size_t)b * 3 * RN;
        float x = Q[base + n], y = Q[base + RN + n], z = Q[base + 2 * RN + n];
        qp[gid] = make_float4(x, y, z, fmaf(x, x, fmaf(y, y, z * z)));
    }
}

__global__ void k_w2bf(const float* __restrict__ W2, ushort* __restrict__ W2b) {
    int i = blockIdx.x * 256 + threadIdx.x;
    if (i < 128 * 192) W2b[i] = f2bf(W2[i]);
}

__global__ void k_transpose(const float* __restrict__ FE, ushort* __restrict__ ftb) {
    __shared__ float t[32][33];
    int bid = blockIdx.x;
    int b = bid >> 9;
    int cb = (bid >> 7) & 3;
    int nb = bid & 127;
    int c0 = cb * 32, n0 = nb * 32;
    int tid = threadIdx.x;
    for (int o = tid; o < 1024; o += 256) {
        int i = o >> 5, j = o & 31;
        t[i][j] = FE[((size_t)b * CC + c0 + i) * RN + n0 + j];
    }
    __syncthreads();
    for (int o = tid; o < 512; o += 256) {
        int j = o >> 4, i2 = (o & 15) * 2;
        uint p = (uint)f2bf(t[i2][j]) | ((uint)f2bf(t[i2 + 1][j]) << 16);
        *(uint*)(ftb + ((size_t)(b * RN + n0 + j) * 128 + c0 + i2)) = p;
    }
}

// One wave per query row. Distributed sorted top-16: lane k holds k-th smallest (d2,idx).
__global__ __launch_bounds__(256) void k_knn(const float4* __restrict__ qp, int* __restrict__ idxout,
                                             float* __restrict__ zwout, float* __restrict__ statslots,
                                             const float* __restrict__ Ww, const float* __restrict__ bw) {
    __shared__ float4 tile[256];
    __shared__ float bacc[9];
    const int tid = threadIdx.x;
    if (tid < 9) bacc[tid] = 0.f;
    const int lane = tid & 63;
    const int wid = tid >> 6;
    const int row = blockIdx.x * 4 + wid;
    const int b = row >> 12, n = row & (RN - 1);
    const float4* qb = qp + b * RN;
    const float4 self = qb[n];
    float ld = 3.4e38f; int li = 0x7FFFFFFF;
    float g15d = 3.4e38f; int g15i = 0x7FFFFFFF;

    for (int t0 = 0; t0 < RN; t0 += 256) {
        __syncthreads();
        tile[tid] = qb[t0 + tid];
        __syncthreads();
        for (int s = 0; s < 256; s += 64) {
            const int m = t0 + s + lane;
            float4 cp = tile[s + lane];
            float d2 = self.w + cp.w - 2.f * fmaf(self.x, cp.x, fmaf(self.y, cp.y, self.z * cp.z));
            bool beats = (d2 < g15d) || (d2 == g15d && m < g15i);
            unsigned long long mask = __ballot(beats);
            while (mask) {
                int src = (int)__builtin_ctzll(mask);
                mask &= mask - 1;
                float cd = __shfl(d2, src);
                int   ci = __shfl(m, src);
                bool lt2 = (ld < cd) || (ld == cd && li < ci);
                int p = (int)__builtin_popcountll(__ballot(lt2) & 0xFFFFull);
                float sd = __shfl_up(ld, 1);
                int   si = __shfl_up(li, 1);
                if (lane == p)      { ld = cd; li = ci; }
                else if (lane > p)  { ld = sd; li = si; }
            }
            g15d = __shfl(ld, 15); g15i = __shfl(li, 15);
        }
    }

    float sx = 0.f, sy = 0.f, sz = 0.f;
    if (lane < 16) {
        idxout[row * 16 + lane] = li;
        float4 pn = qb[li];
        sx = pn.x - self.x; sy = pn.y - self.y; sz = pn.z - self.z;
        float zw = fmaf(Ww[lane * 3], sx, fmaf(Ww[lane * 3 + 1], sy, fmaf(Ww[lane * 3 + 2], sz, bw[lane])));
        zwout[row * 16 + lane] = zw;
    }
    float vals[9] = {sx, sy, sz, sx * sx, sx * sy, sx * sz, sy * sy, sy * sz, sz * sz};
    #pragma unroll
    for (int i = 0; i < 9; ++i) {
        float v = vals[i];
        for (int off = 32; off; off >>= 1) v += __shfl_down(v, off);
        if (lane == 0) atomicAdd(&bacc[i], v);
    }
    __syncthreads();
    if (tid < 9) atomicAdd(&statslots[(blockIdx.x & 63) * 12 + tid], bacc[tid]);
}

// Analytic BN1 / BNw stats from the 12 moments.
__global__ void k_bn1(const float* __restrict__ slots, const float* __restrict__ W1, const float* __restrict__ b1,
                      const float* __restrict__ g1, const float* __restrict__ be1,
                      const float* __restrict__ Ww, const float* __restrict__ bw,
                      const float* __restrict__ gw, const float* __restrict__ bew, float* __restrict__ par) {
    __shared__ float st[12];
    int tid = threadIdx.x;
    if (tid < 12) {
        float s = 0.f;
        for (int i = 0; i < 64; ++i) s += slots[i * 12 + tid];
        st[tid] = s;
    }
    __syncthreads();
    const float invN = 1.0f / (float)NROWS;
    float mx = st[0] * invN, my = st[1] * invN, mz = st[2] * invN;
    float Cxx = st[3] * invN - mx * mx, Cxy = st[4] * invN - mx * my, Cxz = st[5] * invN - mx * mz;
    float Cyy = st[6] * invN - my * my, Cyz = st[7] * invN - my * mz, Czz = st[8] * invN - mz * mz;
    if (tid < 64) {
        float w0 = W1[tid * 3], w1 = W1[tid * 3 + 1], w2 = W1[tid * 3 + 2];
        float mean = w0 * mx + w1 * my + w2 * mz + b1[tid];
        float var = w0 * w0 * Cxx + w1 * w1 * Cyy + w2 * w2 * Czz
                  + 2.f * (w0 * w1 * Cxy + w0 * w2 * Cxz + w1 * w2 * Cyz);
        float sc = g1[tid] * rsqrtf(var + EPSV);
        par[tid] = sc;
        par[64 + tid] = be1[tid] - mean * sc;
    } else if (tid < 80) {
        int k = tid - 64;
        float w0 = Ww[k * 3], w1 = Ww[k * 3 + 1], w2 = Ww[k * 3 + 2];
        float mean = w0 * mx + w1 * my + w2 * mz + bw[k];
        float var = w0 * w0 * Cxx + w1 * w1 * Cyy + w2 * w2 * Czz
                  + 2.f * (w0 * w1 * Cxy + w0 * w2 * Cxz + w1 * w2 * Cyz);
        float sc = gw[k] * rsqrtf(var + EPSV);
        par[128 + k] = sc;
        par[144 + k] = bew[k] - mean * sc;
    }
}

// Fused MFMA GEMM: concat tile (bf16, LDS) x W2 (bf16, registers) -> z2 (bf16) + BN2 partial stats.
// A-operand = W2 rows (M dim = channel), B-operand = concat rows (N dim = row).
// D mapping (m89): col = lane&15 = row, row = (lane>>4)*4+reg = channel -> 8B packed z2 stores.
__global__ __launch_bounds__(256) void k_main(const ushort* __restrict__ ftb, const int* __restrict__ idxb,
                                              const float4* __restrict__ qp, const float* __restrict__ W1,
                                              const float* __restrict__ b1, const ushort* __restrict__ W2b,
                                              const float* __restrict__ b2, const float* __restrict__ par,
                                              float* __restrict__ bn2slots, __hip_bfloat16* __restrict__ z2) {
    __shared__ ushort A_lds[64][200];   // [row][k], 400B row stride: 16B aligned, banks +4 mod 32
    __shared__ float subs[64][3];
    __shared__ int nbr[64];
    const int tid = threadIdx.x;
    const int bid = blockIdx.x;
    const int pair0 = bid * 4;          // 4 query rows -> 64 neighbor rows
    const int b = pair0 >> 12;

    if (tid < 64) {
        int g = tid >> 4, k = tid & 15;
        int pair = pair0 + g;
        int n = idxb[pair * 16 + k];
        nbr[tid] = n;
        float4 pn = qp[b * RN + n];
        float4 ps = qp[pair];
        subs[tid][0] = pn.x - ps.x;
        subs[tid][1] = pn.y - ps.y;
        subs[tid][2] = pn.z - ps.z;
    }
    __syncthreads();
    // grouped_F -> A_lds[:, 0:128]  (contiguous 256B bf16 gathers)
    for (int o = tid; o < 1024; o += 256) {
        int r = o >> 4, c8 = (o & 15) * 8;
        const ushort* src = ftb + ((size_t)(b * RN + nbr[r]) * 128 + c8);
        *(short8*)&A_lds[r][c8] = *(const short8*)src;
    }
    // enc_sub -> A_lds[:, 128:192]
    for (int o = tid; o < 2048; o += 256) {
        int r = o >> 5, c2 = (o & 31) * 2;
        float z0 = fmaf(W1[c2 * 3],     subs[r][0], fmaf(W1[c2 * 3 + 1], subs[r][1], fmaf(W1[c2 * 3 + 2], subs[r][2], b1[c2])));
        float z1 = fmaf(W1[c2 * 3 + 3], subs[r][0], fmaf(W1[c2 * 3 + 4], subs[r][1], fmaf(W1[c2 * 3 + 5], subs[r][2], b1[c2 + 1])));
        float e0 = fmaxf(fmaf(z0, par[c2],     par[64 + c2]),     0.f);
        float e1 = fmaxf(fmaf(z1, par[c2 + 1], par[64 + c2 + 1]), 0.f);
        *(uint*)&A_lds[r][128 + c2] = (uint)f2bf(e0) | ((uint)f2bf(e1) << 16);
    }
    __syncthreads();

    const int lane = tid & 63, w = tid >> 6;
    const int lr = lane & 15, lg = lane >> 4;
    const int cbase = w * 32;

    // A fragments: W2b[cbase + ct*16 + lr][kt*32 + lg*8 + i]
    short8 af[12];
    #pragma unroll
    for (int ct = 0; ct < 2; ++ct)
        #pragma unroll
        for (int kt = 0; kt < 6; ++kt)
            af[ct * 6 + kt] = *(const short8*)(W2b + (size_t)(cbase + ct * 16 + lr) * 192 + kt * 32 + lg * 8);

    float4 b2v[2];
    b2v[0] = *(const float4*)&b2[cbase + lg * 4];
    b2v[1] = *(const float4*)&b2[cbase + 16 + lg * 4];

    float st_s[8], st_q[8];
    #pragma unroll
    for (int i = 0; i < 8; ++i) { st_s[i] = 0.f; st_q[i] = 0.f; }

    #pragma unroll
    for (int nt = 0; nt < 4; ++nt) {
        short8 bf[6];
        #pragma unroll
        for (int kt = 0; kt < 6; ++kt)
            bf[kt] = *(const short8*)&A_lds[nt * 16 + lr][kt * 32 + lg * 8];
        #pragma unroll
        for (int ct = 0; ct < 2; ++ct) {
            f32x4 acc = {0.f, 0.f, 0.f, 0.f};
            #pragma unroll
            for (int kt = 0; kt < 6; ++kt)
                acc = __builtin_amdgcn_mfma_f32_16x16x32_bf16(af[ct * 6 + kt], bf[kt], acc, 0, 0, 0);
            const int c0 = cbase + ct * 16 + lg * 4;
            const size_t row = (size_t)pair0 * 16 + nt * 16 + lr;
            union { __hip_bfloat16 h[4]; uint2 u2; } pk;
            const float4 bb = b2v[ct];
            float vb[4] = {bb.x, bb.y, bb.z, bb.w};
            #pragma unroll
            for (int cc = 0; cc < 4; ++cc) {
                float v = acc[cc] + vb[cc];
                st_s[ct * 4 + cc] += v;
                st_q[ct * 4 + cc] = fmaf(v, v, st_q[ct * 4 + cc]);
                pk.h[cc] = __float2bfloat16(v);
            }
            *(uint2*)(z2 + row * CC + c0) = pk.u2;
        }
    }
    // stats: sum over the 16 rows (lr) per lane group, then one atomic per channel
    #pragma unroll
    for (int i = 0; i < 8; ++i) {
        float s = st_s[i], q = st_q[i];
        #pragma unroll
        for (int m = 1; m < 16; m <<= 1) { s += __shfl_xor(s, m); q += __shfl_xor(q, m); }
        if (lr == 0) {
            int ct = i >> 2, cc = i & 3;
            int c = cbase + ct * 16 + lg * 4 + cc;
            atomicAdd(&bn2slots[(bid & 63) * 256 + c * 2], s);
            atomicAdd(&bn2slots[(bid & 63) * 256 + c * 2 + 1], q);
        }
    }
}

__global__ void k_bn2(const float* __restrict__ slots, const float* __restrict__ g2,
                      const float* __restrict__ be2, float* __restrict__ par) {
    __shared__ float red[256];
    int tid = threadIdx.x;
    float v = 0.f;
    for (int s = 0; s < 64; ++s) v += slots[s * 256 + tid];
    red[tid] = v;
    __syncthreads();
    if (tid < 128) {
        const float invN = 1.0f / (float)NROWS;
        float mean = red[2 * tid] * invN;
        float var = red[2 * tid + 1] * invN - mean * mean;
        float sc = g2[tid] * rsqrtf(var + EPSV);
        par[160 + tid] = sc;
        par[288 + tid] = be2[tid] - mean * sc;
    }
}

// Epilogue: BN2+ReLU, weight by w_diag, sum over K, residual, transpose to (B,C,N).
__global__ __launch_bounds__(256) void k_out(const __hip_bfloat16* __restrict__ z2, const float* __restrict__ zw_raw,
                                             const float* __restrict__ par, const float* __restrict__ F_E,
                                             float* __restrict__ out) {
    __shared__ float wd[32][16];
    __shared__ float outs[32][129];
    const int tid = threadIdx.x;
    const int b = blockIdx.x >> 7;
    const int r0 = (blockIdx.x & 127) * 32;
    const int rowbase = (b * RN + r0) * 16;
    for (int o = tid; o < 512; o += 256) {
        int rr = o >> 4, k = o & 15;
        wd[rr][k] = fmaxf(fmaf(zw_raw[rowbase + o], par[128 + k], par[144 + k]), 0.f);
    }
    __syncthreads();
    const int c0 = (tid & 63) * 2;
    const int rh = tid >> 6;
    const float sc0 = par[160 + c0], sh0 = par[288 + c0];
    const float sc1 = par[160 + c0 + 1], sh1 = par[288 + c0 + 1];
    for (int rr = rh; rr < 32; rr += 4) {
        float a0 = 0.f, a1 = 0.f;
        const __hip_bfloat16* zp = z2 + ((size_t)rowbase + rr * 16) * CC + c0;
        #pragma unroll
        for (int k = 0; k < 16; ++k) {
            unsigned int uu = *(const unsigned int*)(zp + k * CC);
            float z0 = __uint_as_float(uu << 16);
            float z1 = __uint_as_float(uu & 0xFFFF0000u);
            float w = wd[rr][k];
            a0 += fmaxf(fmaf(z0, sc0, sh0), 0.f) * w;
            a1 += fmaxf(fmaf(z1, sc1, sh1), 0.f) * w;
        }
        outs[rr][c0] = a0; outs[rr][c0 + 1] = a1;
    }
    __syncthreads();
    for (int o = tid; o < 4096; o += 256) {
        int c = o >> 5, rr = o & 31;
        size_t oi = ((size_t)b * CC + c) * RN + r0 + rr;
        out[oi] = outs[rr][c] + F_E[oi];
    }
}

extern "C" void kernel_launch(void* const* d_in, const int* in_sizes, int n_in,
                              void* d_out, int out_size, void* d_ws, size_t ws_size,
                              hipStream_t stream) {
    const float* F_E = (const float*)d_in[0];
    const float* Qp  = (const float*)d_in[1];
    const float* W1  = (const float*)d_in[2];
    const float* b1  = (const float*)d_in[3];
    const float* g1  = (const float*)d_in[4];
    const float* be1 = (const float*)d_in[5];
    const float* W2  = (const float*)d_in[6];
    const float* b2  = (const float*)d_in[7];
    const float* g2  = (const float*)d_in[8];
    const float* be2 = (const float*)d_in[9];
    const float* Ww  = (const float*)d_in[10];
    const float* bw  = (const float*)d_in[11];
    const float* gw  = (const float*)d_in[12];
    const float* bew = (const float*)d_in[13];
    float* out = (float*)d_out;
    float* wsf = (float*)d_ws;

    float* bn2slots   = wsf;
    float* statslots  = wsf + 16384;
    float* par        = wsf + 17152;
    ushort* W2b       = (ushort*)(wsf + 17664);
    float4* qpack     = (float4*)(wsf + 32768);
    int* idxb         = (int*)(wsf + 98304);
    float* zw_raw     = wsf + 360448;
    ushort* ftb       = (ushort*)(wsf + 622592);
    __hip_bfloat16* z2 = (__hip_bfloat16*)(wsf + 1671168);

    hipMemsetAsync(d_ws, 0, 17152 * sizeof(float), stream);
    k_prep<<<64, 256, 0, stream>>>(Qp, qpack);
    k_w2bf<<<96, 256, 0, stream>>>(W2, W2b);
    k_transpose<<<2048, 256, 0, stream>>>(F_E, ftb);
    k_knn<<<4096, 256, 0, stream>>>(qpack, idxb, zw_raw, statslots, Ww, bw);
    k_bn1<<<1, 128, 0, stream>>>(statslots, W1, b1, g1, be1, Ww, bw, gw, bew, par);
    k_main<<<4096, 256, 0, stream>>>(ftb, idxb, qpack, W1, b1, W2b, b2, par, bn2slots, z2);
    k_bn2<<<1, 256, 0, stream>>>(bn2slots, g2, be2, par);
    k_out<<<512, 256, 0, stream>>>(z2, zw_raw, par, F_E, out);
}

// Round 3
// 270.743 us; speedup vs baseline: 2.2780x; 1.2220x over previous
//
#include <hip/hip_runtime.h>
#include <hip/hip_bf16.h>

// Problem constants
#define BB 4
#define CC 128
#define RN 4096
#define KK 16
#define NROWS (BB*RN*KK)   // 262144
#define EPSV 1e-5f

typedef __attribute__((ext_vector_type(8))) short short8;
typedef __attribute__((ext_vector_type(4))) float f32x4;

__device__ inline ushort f2bf(float f) {
    union { __hip_bfloat16 h; ushort u; } cv;
    cv.h = __float2bfloat16(f);
    return cv.u;
}

// ---------------- workspace layout (float indices) ----------------
// [0, 16384)          bn2 slots: 64 slots x 128 ch x {sum, sumsq}
// [16384, 17152)      stat slots: 64 slots x 12
// [17152, 17568)      params: scale1[64] shift1[64] scalew[16] shiftw[16] scale2[128] shift2[128]
// [17664, 29952)      W2 bf16 (128x192 ushort)
// [32768, 98304)      qpack: 16384 x float4
// [98304, 360448)     idx: 262144 int
// [360448, 622592)    zw_raw: 262144 f32
// [622592, 1671168)   ft bf16: (B,N,128) ushort
// [1671168, ...)      z2: 262144 x 128 bf16 (67.1 MB)

__global__ void k_prep(const float* __restrict__ Q, float4* __restrict__ qp) {
    int gid = blockIdx.x * 256 + threadIdx.x;
    if (gid < BB * RN) {
        int b = gid >> 12, n = gid & (RN - 1);
        size_t base = (size_t)b * 3 * RN;
        float x = Q[base + n], y = Q[base + RN + n], z = Q[base + 2 * RN + n];
        qp[gid] = make_float4(x, y, z, fmaf(x, x, fmaf(y, y, z * z)));
    }
}

__global__ void k_w2bf(const float* __restrict__ W2, ushort* __restrict__ W2b) {
    int i = blockIdx.x * 256 + threadIdx.x;
    if (i < 128 * 192) W2b[i] = f2bf(W2[i]);
}

__global__ void k_transpose(const float* __restrict__ FE, ushort* __restrict__ ftb) {
    __shared__ float t[32][33];
    int bid = blockIdx.x;
    int b = bid >> 9;
    int cb = (bid >> 7) & 3;
    int nb = bid & 127;
    int c0 = cb * 32, n0 = nb * 32;
    int tid = threadIdx.x;
    for (int o = tid; o < 1024; o += 256) {
        int i = o >> 5, j = o & 31;
        t[i][j] = FE[((size_t)b * CC + c0 + i) * RN + n0 + j];
    }
    __syncthreads();
    for (int o = tid; o < 512; o += 256) {
        int j = o >> 4, i2 = (o & 15) * 2;
        uint p = (uint)f2bf(t[i2][j]) | ((uint)f2bf(t[i2 + 1][j]) << 16);
        *(uint*)(ftb + ((size_t)(b * RN + n0 + j) * 128 + c0 + i2)) = p;
    }
}

// One wave per query row, no inter-wave coupling.
// Init: bitonic sort of first 64 candidates by (d2,idx) across lanes.
// Scan: ballot + sorted-insert into the distributed top-16 (lanes 0..15).
__global__ __launch_bounds__(256) void k_knn(const float4* __restrict__ qp, int* __restrict__ idxout,
                                             float* __restrict__ zwout, float* __restrict__ statslots,
                                             const float* __restrict__ Ww, const float* __restrict__ bw) {
    __shared__ float bacc[9];
    const int tid = threadIdx.x;
    if (tid < 9) bacc[tid] = 0.f;
    __syncthreads();
    const int lane = tid & 63;
    const int wid = tid >> 6;
    const int row = blockIdx.x * 4 + wid;
    const int b = row >> 12, n = row & (RN - 1);
    const float4* qb = qp + b * RN;
    const float4 self = qb[n];

    float ld; int li;
    {   // ---- bitonic sort of candidates 0..63 by (d2, idx) ascending ----
        float4 cp = qb[lane];
        ld = self.w + cp.w - 2.f * fmaf(self.x, cp.x, fmaf(self.y, cp.y, self.z * cp.z));
        li = lane;
        #pragma unroll
        for (int k = 2; k <= 64; k <<= 1) {
            #pragma unroll
            for (int j = k >> 1; j > 0; j >>= 1) {
                float od = __shfl_xor(ld, j);
                int   oi = __shfl_xor(li, j);
                bool up    = ((lane & k) == 0);
                bool lower = ((lane & j) == 0);
                bool myless = (ld < od) || (ld == od && li < oi);
                bool keep = (myless == lower) == up;
                if (!keep) { ld = od; li = oi; }
            }
        }
    }
    float g15d = __shfl(ld, 15); int g15i = __shfl(li, 15);

    float4 cur = qb[64 + lane];
    for (int t0 = 64; t0 < RN; t0 += 64) {
        float4 nxt = qb[t0 + 64 + lane];   // prefetch; last-iter overrun lands in ws, never used
        const int m = t0 + lane;
        float d2 = self.w + cur.w - 2.f * fmaf(self.x, cur.x, fmaf(self.y, cur.y, self.z * cur.z));
        bool beats = (d2 < g15d) || (d2 == g15d && m < g15i);
        unsigned long long mask = __ballot(beats);
        if (mask) {
            do {
                int src = (int)__builtin_ctzll(mask);
                mask &= mask - 1;
                float cd = __shfl(d2, src);
                int   ci = __shfl(m, src);
                bool lt2 = (ld < cd) || (ld == cd && li < ci);
                int p = (int)__builtin_popcountll(__ballot(lt2) & 0xFFFFull);
                float sd = __shfl_up(ld, 1);
                int   si = __shfl_up(li, 1);
                if (lane == p)      { ld = cd; li = ci; }
                else if (lane > p)  { ld = sd; li = si; }
            } while (mask);
            g15d = __shfl(ld, 15); g15i = __shfl(li, 15);
        }
        cur = nxt;
    }

    float sx = 0.f, sy = 0.f, sz = 0.f;
    if (lane < 16) {
        idxout[row * 16 + lane] = li;
        float4 pn = qb[li];
        sx = pn.x - self.x; sy = pn.y - self.y; sz = pn.z - self.z;
        float zw = fmaf(Ww[lane * 3], sx, fmaf(Ww[lane * 3 + 1], sy, fmaf(Ww[lane * 3 + 2], sz, bw[lane])));
        zwout[row * 16 + lane] = zw;
    }
    float vals[9] = {sx, sy, sz, sx * sx, sx * sy, sx * sz, sy * sy, sy * sz, sz * sz};
    #pragma unroll
    for (int i = 0; i < 9; ++i) {
        float v = vals[i];
        for (int off = 32; off; off >>= 1) v += __shfl_down(v, off);
        if (lane == 0) atomicAdd(&bacc[i], v);
    }
    __syncthreads();
    if (tid < 9) atomicAdd(&statslots[(blockIdx.x & 63) * 12 + tid], bacc[tid]);
}

// Analytic BN1 / BNw stats from the 12 moments.
__global__ void k_bn1(const float* __restrict__ slots, const float* __restrict__ W1, const float* __restrict__ b1,
                      const float* __restrict__ g1, const float* __restrict__ be1,
                      const float* __restrict__ Ww, const float* __restrict__ bw,
                      const float* __restrict__ gw, const float* __restrict__ bew, float* __restrict__ par) {
    __shared__ float st[12];
    int tid = threadIdx.x;
    if (tid < 12) {
        float s = 0.f;
        for (int i = 0; i < 64; ++i) s += slots[i * 12 + tid];
        st[tid] = s;
    }
    __syncthreads();
    const float invN = 1.0f / (float)NROWS;
    float mx = st[0] * invN, my = st[1] * invN, mz = st[2] * invN;
    float Cxx = st[3] * invN - mx * mx, Cxy = st[4] * invN - mx * my, Cxz = st[5] * invN - mx * mz;
    float Cyy = st[6] * invN - my * my, Cyz = st[7] * invN - my * mz, Czz = st[8] * invN - mz * mz;
    if (tid < 64) {
        float w0 = W1[tid * 3], w1 = W1[tid * 3 + 1], w2 = W1[tid * 3 + 2];
        float mean = w0 * mx + w1 * my + w2 * mz + b1[tid];
        float var = w0 * w0 * Cxx + w1 * w1 * Cyy + w2 * w2 * Czz
                  + 2.f * (w0 * w1 * Cxy + w0 * w2 * Cxz + w1 * w2 * Cyz);
        float sc = g1[tid] * rsqrtf(var + EPSV);
        par[tid] = sc;
        par[64 + tid] = be1[tid] - mean * sc;
    } else if (tid < 80) {
        int k = tid - 64;
        float w0 = Ww[k * 3], w1 = Ww[k * 3 + 1], w2 = Ww[k * 3 + 2];
        float mean = w0 * mx + w1 * my + w2 * mz + bw[k];
        float var = w0 * w0 * Cxx + w1 * w1 * Cyy + w2 * w2 * Czz
                  + 2.f * (w0 * w1 * Cxy + w0 * w2 * Cxz + w1 * w2 * Cyz);
        float sc = gw[k] * rsqrtf(var + EPSV);
        par[128 + k] = sc;
        par[144 + k] = bew[k] - mean * sc;
    }
}

// Fused MFMA GEMM: concat tile (bf16, LDS) x W2 (bf16, registers) -> z2 (bf16) + BN2 partial stats.
__global__ __launch_bounds__(256) void k_main(const ushort* __restrict__ ftb, const int* __restrict__ idxb,
                                              const float4* __restrict__ qp, const float* __restrict__ W1,
                                              const float* __restrict__ b1, const ushort* __restrict__ W2b,
                                              const float* __restrict__ b2, const float* __restrict__ par,
                                              float* __restrict__ bn2slots, __hip_bfloat16* __restrict__ z2) {
    __shared__ ushort A_lds[64][200];
    __shared__ float subs[64][3];
    __shared__ int nbr[64];
    const int tid = threadIdx.x;
    const int bid = blockIdx.x;
    const int pair0 = bid * 4;
    const int b = pair0 >> 12;

    if (tid < 64) {
        int g = tid >> 4, k = tid & 15;
        int pair = pair0 + g;
        int n = idxb[pair * 16 + k];
        nbr[tid] = n;
        float4 pn = qp[b * RN + n];
        float4 ps = qp[pair];
        subs[tid][0] = pn.x - ps.x;
        subs[tid][1] = pn.y - ps.y;
        subs[tid][2] = pn.z - ps.z;
    }
    __syncthreads();
    for (int o = tid; o < 1024; o += 256) {
        int r = o >> 4, c8 = (o & 15) * 8;
        const ushort* src = ftb + ((size_t)(b * RN + nbr[r]) * 128 + c8);
        *(short8*)&A_lds[r][c8] = *(const short8*)src;
    }
    for (int o = tid; o < 2048; o += 256) {
        int r = o >> 5, c2 = (o & 31) * 2;
        float z0 = fmaf(W1[c2 * 3],     subs[r][0], fmaf(W1[c2 * 3 + 1], subs[r][1], fmaf(W1[c2 * 3 + 2], subs[r][2], b1[c2])));
        float z1 = fmaf(W1[c2 * 3 + 3], subs[r][0], fmaf(W1[c2 * 3 + 4], subs[r][1], fmaf(W1[c2 * 3 + 5], subs[r][2], b1[c2 + 1])));
        float e0 = fmaxf(fmaf(z0, par[c2],     par[64 + c2]),     0.f);
        float e1 = fmaxf(fmaf(z1, par[c2 + 1], par[64 + c2 + 1]), 0.f);
        *(uint*)&A_lds[r][128 + c2] = (uint)f2bf(e0) | ((uint)f2bf(e1) << 16);
    }
    __syncthreads();

    const int lane = tid & 63, w = tid >> 6;
    const int lr = lane & 15, lg = lane >> 4;
    const int cbase = w * 32;

    short8 af[12];
    #pragma unroll
    for (int ct = 0; ct < 2; ++ct)
        #pragma unroll
        for (int kt = 0; kt < 6; ++kt)
            af[ct * 6 + kt] = *(const short8*)(W2b + (size_t)(cbase + ct * 16 + lr) * 192 + kt * 32 + lg * 8);

    float4 b2v[2];
    b2v[0] = *(const float4*)&b2[cbase + lg * 4];
    b2v[1] = *(const float4*)&b2[cbase + 16 + lg * 4];

    float st_s[8], st_q[8];
    #pragma unroll
    for (int i = 0; i < 8; ++i) { st_s[i] = 0.f; st_q[i] = 0.f; }

    #pragma unroll
    for (int nt = 0; nt < 4; ++nt) {
        short8 bf[6];
        #pragma unroll
        for (int kt = 0; kt < 6; ++kt)
            bf[kt] = *(const short8*)&A_lds[nt * 16 + lr][kt * 32 + lg * 8];
        #pragma unroll
        for (int ct = 0; ct < 2; ++ct) {
            f32x4 acc = {0.f, 0.f, 0.f, 0.f};
            #pragma unroll
            for (int kt = 0; kt < 6; ++kt)
                acc = __builtin_amdgcn_mfma_f32_16x16x32_bf16(af[ct * 6 + kt], bf[kt], acc, 0, 0, 0);
            const int c0 = cbase + ct * 16 + lg * 4;
            const size_t row = (size_t)pair0 * 16 + nt * 16 + lr;
            union { __hip_bfloat16 h[4]; uint2 u2; } pk;
            const float4 bb = b2v[ct];
            float vb[4] = {bb.x, bb.y, bb.z, bb.w};
            #pragma unroll
            for (int cc = 0; cc < 4; ++cc) {
                float v = acc[cc] + vb[cc];
                st_s[ct * 4 + cc] += v;
                st_q[ct * 4 + cc] = fmaf(v, v, st_q[ct * 4 + cc]);
                pk.h[cc] = __float2bfloat16(v);
            }
            *(uint2*)(z2 + row * CC + c0) = pk.u2;
        }
    }
    #pragma unroll
    for (int i = 0; i < 8; ++i) {
        float s = st_s[i], q = st_q[i];
        #pragma unroll
        for (int m = 1; m < 16; m <<= 1) { s += __shfl_xor(s, m); q += __shfl_xor(q, m); }
        if (lr == 0) {
            int ct = i >> 2, cc = i & 3;
            int c = cbase + ct * 16 + lg * 4 + cc;
            atomicAdd(&bn2slots[(bid & 63) * 256 + c * 2], s);
            atomicAdd(&bn2slots[(bid & 63) * 256 + c * 2 + 1], q);
        }
    }
}

__global__ void k_bn2(const float* __restrict__ slots, const float* __restrict__ g2,
                      const float* __restrict__ be2, float* __restrict__ par) {
    __shared__ float red[256];
    int tid = threadIdx.x;
    float v = 0.f;
    for (int s = 0; s < 64; ++s) v += slots[s * 256 + tid];
    red[tid] = v;
    __syncthreads();
    if (tid < 128) {
        const float invN = 1.0f / (float)NROWS;
        float mean = red[2 * tid] * invN;
        float var = red[2 * tid + 1] * invN - mean * mean;
        float sc = g2[tid] * rsqrtf(var + EPSV);
        par[160 + tid] = sc;
        par[288 + tid] = be2[tid] - mean * sc;
    }
}

// Epilogue: BN2+ReLU, weight by w_diag, sum over K, residual, transpose to (B,C,N).
__global__ __launch_bounds__(256) void k_out(const __hip_bfloat16* __restrict__ z2, const float* __restrict__ zw_raw,
                                             const float* __restrict__ par, const float* __restrict__ F_E,
                                             float* __restrict__ out) {
    __shared__ float wd[32][16];
    __shared__ float outs[32][129];
    const int tid = threadIdx.x;
    const int b = blockIdx.x >> 7;
    const int r0 = (blockIdx.x & 127) * 32;
    const int rowbase = (b * RN + r0) * 16;
    for (int o = tid; o < 512; o += 256) {
        int rr = o >> 4, k = o & 15;
        wd[rr][k] = fmaxf(fmaf(zw_raw[rowbase + o], par[128 + k], par[144 + k]), 0.f);
    }
    __syncthreads();
    const int c0 = (tid & 63) * 2;
    const int rh = tid >> 6;
    const float sc0 = par[160 + c0], sh0 = par[288 + c0];
    const float sc1 = par[160 + c0 + 1], sh1 = par[288 + c0 + 1];
    for (int rr = rh; rr < 32; rr += 4) {
        float a0 = 0.f, a1 = 0.f;
        const __hip_bfloat16* zp = z2 + ((size_t)rowbase + rr * 16) * CC + c0;
        #pragma unroll
        for (int k = 0; k < 16; ++k) {
            unsigned int uu = *(const unsigned int*)(zp + k * CC);
            float z0 = __uint_as_float(uu << 16);
            float z1 = __uint_as_float(uu & 0xFFFF0000u);
            float w = wd[rr][k];
            a0 += fmaxf(fmaf(z0, sc0, sh0), 0.f) * w;
            a1 += fmaxf(fmaf(z1, sc1, sh1), 0.f) * w;
        }
        outs[rr][c0] = a0; outs[rr][c0 + 1] = a1;
    }
    __syncthreads();
    for (int o = tid; o < 4096; o += 256) {
        int c = o >> 5, rr = o & 31;
        size_t oi = ((size_t)b * CC + c) * RN + r0 + rr;
        out[oi] = outs[rr][c] + F_E[oi];
    }
}

extern "C" void kernel_launch(void* const* d_in, const int* in_sizes, int n_in,
                              void* d_out, int out_size, void* d_ws, size_t ws_size,
                              hipStream_t stream) {
    const float* F_E = (const float*)d_in[0];
    const float* Qp  = (const float*)d_in[1];
    const float* W1  = (const float*)d_in[2];
    const float* b1  = (const float*)d_in[3];
    const float* g1  = (const float*)d_in[4];
    const float* be1 = (const float*)d_in[5];
    const float* W2  = (const float*)d_in[6];
    const float* b2  = (const float*)d_in[7];
    const float* g2  = (const float*)d_in[8];
    const float* be2 = (const float*)d_in[9];
    const float* Ww  = (const float*)d_in[10];
    const float* bw  = (const float*)d_in[11];
    const float* gw  = (const float*)d_in[12];
    const float* bew = (const float*)d_in[13];
    float* out = (float*)d_out;
    float* wsf = (float*)d_ws;

    float* bn2slots   = wsf;
    float* statslots  = wsf + 16384;
    float* par        = wsf + 17152;
    ushort* W2b       = (ushort*)(wsf + 17664);
    float4* qpack     = (float4*)(wsf + 32768);
    int* idxb         = (int*)(wsf + 98304);
    float* zw_raw     = wsf + 360448;
    ushort* ftb       = (ushort*)(wsf + 622592);
    __hip_bfloat16* z2 = (__hip_bfloat16*)(wsf + 1671168);

    hipMemsetAsync(d_ws, 0, 17152 * sizeof(float), stream);
    k_prep<<<64, 256, 0, stream>>>(Qp, qpack);
    k_w2bf<<<96, 256, 0, stream>>>(W2, W2b);
    k_transpose<<<2048, 256, 0, stream>>>(F_E, ftb);
    k_knn<<<4096, 256, 0, stream>>>(qpack, idxb, zw_raw, statslots, Ww, bw);
    k_bn1<<<1, 128, 0, stream>>>(statslots, W1, b1, g1, be1, Ww, bw, gw, bew, par);
    k_main<<<4096, 256, 0, stream>>>(ftb, idxb, qpack, W1, b1, W2b, b2, par, bn2slots, z2);
    k_bn2<<<1, 256, 0, stream>>>(bn2slots, g2, be2, par);
    k_out<<<512, 256, 0, stream>>>(z2, zw_raw, par, F_E, out);
}

// Round 4
// 254.793 us; speedup vs baseline: 2.4206x; 1.0626x over previous
//
#include <hip/hip_runtime.h>
#include <hip/hip_bf16.h>

// Problem constants
#define BB 4
#define CC 128
#define RN 4096
#define KK 16
#define NROWS (BB*RN*KK)   // 262144
#define EPSV 1e-5f

typedef __attribute__((ext_vector_type(8))) short short8;
typedef __attribute__((ext_vector_type(4))) float f32x4;

__device__ inline ushort f2bf(float f) {
    union { __hip_bfloat16 h; ushort u; } cv;
    cv.h = __float2bfloat16(f);
    return cv.u;
}

__device__ inline float readlane_f(float v, int src) {
    return __uint_as_float((uint)__builtin_amdgcn_readlane((int)__float_as_uint(v), src));
}

// ---------------- workspace layout (float indices) ----------------
// [0, 16384)          bn2 slots: 64 slots x 128 ch x {sum, sumsq}
// [16384, 17152)      stat slots: 64 slots x 12
// [17152, 17568)      params: scale1[64] shift1[64] scalew[16] shiftw[16] scale2[128] shift2[128]
// [17664, 29952)      W2 bf16 (128x192 ushort)
// [32768, 98304)      qpack: 16384 x float4
// [98304, 360448)     idx: 262144 int
// [360448, 622592)    zw_raw: 262144 f32
// [622592, 1671168)   ft bf16: (B,N,128) ushort
// [1671168, ...)      z2: 262144 x 128 bf16 (67.1 MB)

// merged: blocks [0,64) do qpack prep; blocks [64,160) do W2 bf16 cast
__global__ void k_prep(const float* __restrict__ Q, float4* __restrict__ qp,
                       const float* __restrict__ W2, ushort* __restrict__ W2b) {
    int blk = blockIdx.x;
    if (blk < 64) {
        int gid = blk * 256 + threadIdx.x;
        int b = gid >> 12, n = gid & (RN - 1);
        size_t base = (size_t)b * 3 * RN;
        float x = Q[base + n], y = Q[base + RN + n], z = Q[base + 2 * RN + n];
        qp[gid] = make_float4(x, y, z, fmaf(x, x, fmaf(y, y, z * z)));
    } else {
        int i = (blk - 64) * 256 + threadIdx.x;
        if (i < 128 * 192) W2b[i] = f2bf(W2[i]);
    }
}

__global__ void k_transpose(const float* __restrict__ FE, ushort* __restrict__ ftb) {
    __shared__ float t[32][33];
    int bid = blockIdx.x;
    int b = bid >> 9;
    int cb = (bid >> 7) & 3;
    int nb = bid & 127;
    int c0 = cb * 32, n0 = nb * 32;
    int tid = threadIdx.x;
    for (int o = tid; o < 1024; o += 256) {
        int i = o >> 5, j = o & 31;
        t[i][j] = FE[((size_t)b * CC + c0 + i) * RN + n0 + j];
    }
    __syncthreads();
    for (int o = tid; o < 512; o += 256) {
        int j = o >> 4, i2 = (o & 15) * 2;
        uint p = (uint)f2bf(t[i2][j]) | ((uint)f2bf(t[i2 + 1][j]) << 16);
        *(uint*)(ftb + ((size_t)(b * RN + n0 + j) * 128 + c0 + i2)) = p;
    }
}

// One wave per query row. Bitonic-sorted init; scan with ballot; inserts use
// readlane (uniform src -> SGPR broadcast, no ds_bpermute) + early-issued
// ds_bpermute shifts whose latency overlaps the scalar compare chain.
__global__ __launch_bounds__(256) void k_knn(const float4* __restrict__ qp, int* __restrict__ idxout,
                                             float* __restrict__ zwout, float* __restrict__ statslots,
                                             const float* __restrict__ Ww, const float* __restrict__ bw) {
    __shared__ float bacc[9];
    const int tid = threadIdx.x;
    if (tid < 9) bacc[tid] = 0.f;
    __syncthreads();
    const int lane = tid & 63;
    const int wid = tid >> 6;
    const int row = blockIdx.x * 4 + wid;
    const int b = row >> 12, n = row & (RN - 1);
    const float4* qb = qp + b * RN;
    const float4 self = qb[n];
    const int upaddr = ((lane - 1) & 63) << 2;   // ds_bpermute byte addr for shift-up-by-1

    float ld; int li;
    {   // ---- bitonic sort of candidates 0..63 by (d2, idx) ascending ----
        float4 cp = qb[lane];
        ld = self.w + cp.w - 2.f * fmaf(self.x, cp.x, fmaf(self.y, cp.y, self.z * cp.z));
        li = lane;
        #pragma unroll
        for (int k = 2; k <= 64; k <<= 1) {
            #pragma unroll
            for (int j = k >> 1; j > 0; j >>= 1) {
                float od = __shfl_xor(ld, j);
                int   oi = __shfl_xor(li, j);
                bool up    = ((lane & k) == 0);
                bool lower = ((lane & j) == 0);
                bool myless = (ld < od) || (ld == od && li < oi);
                bool keep = (myless == lower) == up;
                if (!keep) { ld = od; li = oi; }
            }
        }
    }
    float g15d = readlane_f(ld, 15);
    int   g15i = __builtin_amdgcn_readlane(li, 15);

    float4 cur = qb[64 + lane];
    for (int t0 = 64; t0 < RN; t0 += 64) {
        float4 nxt = qb[t0 + 64 + lane];   // prefetch; last-iter overrun stays inside ws
        const float d2 = self.w + cur.w - 2.f * fmaf(self.x, cur.x, fmaf(self.y, cur.y, self.z * cur.z));
        bool beats = (d2 < g15d) || (d2 == g15d && (t0 + lane) < g15i);
        unsigned long long mask = __ballot(beats);
        if (mask) {
            do {
                // independent of the candidate: issue shift early, latency overlaps below
                float sd = __uint_as_float((uint)__builtin_amdgcn_ds_bpermute(upaddr, (int)__float_as_uint(ld)));
                int   si = __builtin_amdgcn_ds_bpermute(upaddr, li);
                int src = (int)__builtin_ctzll(mask);
                mask &= mask - 1;
                float cd = readlane_f(d2, src);   // SGPR broadcast
                int   ci = t0 + src;              // pure scalar
                bool lt2 = (ld < cd) || (ld == cd && li < ci);
                int p = (int)__builtin_popcountll(__ballot(lt2) & 0xFFFFull);
                if (lane == p)      { ld = cd; li = ci; }
                else if (lane > p)  { ld = sd; li = si; }
            } while (mask);
            g15d = readlane_f(ld, 15);
            g15i = __builtin_amdgcn_readlane(li, 15);
        }
        cur = nxt;
    }

    float sx = 0.f, sy = 0.f, sz = 0.f;
    if (lane < 16) {
        idxout[row * 16 + lane] = li;
        float4 pn = qb[li];
        sx = pn.x - self.x; sy = pn.y - self.y; sz = pn.z - self.z;
        float zw = fmaf(Ww[lane * 3], sx, fmaf(Ww[lane * 3 + 1], sy, fmaf(Ww[lane * 3 + 2], sz, bw[lane])));
        zwout[row * 16 + lane] = zw;
    }
    float vals[9] = {sx, sy, sz, sx * sx, sx * sy, sx * sz, sy * sy, sy * sz, sz * sz};
    #pragma unroll
    for (int i = 0; i < 9; ++i) {
        float v = vals[i];
        for (int off = 32; off; off >>= 1) v += __shfl_down(v, off);
        if (lane == 0) atomicAdd(&bacc[i], v);
    }
    __syncthreads();
    if (tid < 9) atomicAdd(&statslots[(blockIdx.x & 63) * 12 + tid], bacc[tid]);
}

// Analytic BN1 / BNw stats from the 12 moments.
__global__ void k_bn1(const float* __restrict__ slots, const float* __restrict__ W1, const float* __restrict__ b1,
                      const float* __restrict__ g1, const float* __restrict__ be1,
                      const float* __restrict__ Ww, const float* __restrict__ bw,
                      const float* __restrict__ gw, const float* __restrict__ bew, float* __restrict__ par) {
    __shared__ float st[12];
    int tid = threadIdx.x;
    if (tid < 12) {
        float s = 0.f;
        for (int i = 0; i < 64; ++i) s += slots[i * 12 + tid];
        st[tid] = s;
    }
    __syncthreads();
    const float invN = 1.0f / (float)NROWS;
    float mx = st[0] * invN, my = st[1] * invN, mz = st[2] * invN;
    float Cxx = st[3] * invN - mx * mx, Cxy = st[4] * invN - mx * my, Cxz = st[5] * invN - mx * mz;
    float Cyy = st[6] * invN - my * my, Cyz = st[7] * invN - my * mz, Czz = st[8] * invN - mz * mz;
    if (tid < 64) {
        float w0 = W1[tid * 3], w1 = W1[tid * 3 + 1], w2 = W1[tid * 3 + 2];
        float mean = w0 * mx + w1 * my + w2 * mz + b1[tid];
        float var = w0 * w0 * Cxx + w1 * w1 * Cyy + w2 * w2 * Czz
                  + 2.f * (w0 * w1 * Cxy + w0 * w2 * Cxz + w1 * w2 * Cyz);
        float sc = g1[tid] * rsqrtf(var + EPSV);
        par[tid] = sc;
        par[64 + tid] = be1[tid] - mean * sc;
    } else if (tid < 80) {
        int k = tid - 64;
        float w0 = Ww[k * 3], w1 = Ww[k * 3 + 1], w2 = Ww[k * 3 + 2];
        float mean = w0 * mx + w1 * my + w2 * mz + bw[k];
        float var = w0 * w0 * Cxx + w1 * w1 * Cyy + w2 * w2 * Czz
                  + 2.f * (w0 * w1 * Cxy + w0 * w2 * Cxz + w1 * w2 * Cyz);
        float sc = gw[k] * rsqrtf(var + EPSV);
        par[128 + k] = sc;
        par[144 + k] = bew[k] - mean * sc;
    }
}

// Fused MFMA GEMM: concat tile (bf16, LDS) x W2 (bf16, registers) -> z2 (bf16) + BN2 partial stats.
__global__ __launch_bounds__(256) void k_main(const ushort* __restrict__ ftb, const int* __restrict__ idxb,
                                              const float4* __restrict__ qp, const float* __restrict__ W1,
                                              const float* __restrict__ b1, const ushort* __restrict__ W2b,
                                              const float* __restrict__ b2, const float* __restrict__ par,
                                              float* __restrict__ bn2slots, __hip_bfloat16* __restrict__ z2) {
    __shared__ ushort A_lds[64][200];
    __shared__ float subs[64][3];
    __shared__ int nbr[64];
    const int tid = threadIdx.x;
    const int bid = blockIdx.x;
    const int pair0 = bid * 4;
    const int b = pair0 >> 12;

    if (tid < 64) {
        int g = tid >> 4, k = tid & 15;
        int pair = pair0 + g;
        int n = idxb[pair * 16 + k];
        nbr[tid] = n;
        float4 pn = qp[b * RN + n];
        float4 ps = qp[pair];
        subs[tid][0] = pn.x - ps.x;
        subs[tid][1] = pn.y - ps.y;
        subs[tid][2] = pn.z - ps.z;
    }
    __syncthreads();
    for (int o = tid; o < 1024; o += 256) {
        int r = o >> 4, c8 = (o & 15) * 8;
        const ushort* src = ftb + ((size_t)(b * RN + nbr[r]) * 128 + c8);
        *(short8*)&A_lds[r][c8] = *(const short8*)src;
    }
    for (int o = tid; o < 2048; o += 256) {
        int r = o >> 5, c2 = (o & 31) * 2;
        float z0 = fmaf(W1[c2 * 3],     subs[r][0], fmaf(W1[c2 * 3 + 1], subs[r][1], fmaf(W1[c2 * 3 + 2], subs[r][2], b1[c2])));
        float z1 = fmaf(W1[c2 * 3 + 3], subs[r][0], fmaf(W1[c2 * 3 + 4], subs[r][1], fmaf(W1[c2 * 3 + 5], subs[r][2], b1[c2 + 1])));
        float e0 = fmaxf(fmaf(z0, par[c2],     par[64 + c2]),     0.f);
        float e1 = fmaxf(fmaf(z1, par[c2 + 1], par[64 + c2 + 1]), 0.f);
        *(uint*)&A_lds[r][128 + c2] = (uint)f2bf(e0) | ((uint)f2bf(e1) << 16);
    }
    __syncthreads();

    const int lane = tid & 63, w = tid >> 6;
    const int lr = lane & 15, lg = lane >> 4;
    const int cbase = w * 32;

    short8 af[12];
    #pragma unroll
    for (int ct = 0; ct < 2; ++ct)
        #pragma unroll
        for (int kt = 0; kt < 6; ++kt)
            af[ct * 6 + kt] = *(const short8*)(W2b + (size_t)(cbase + ct * 16 + lr) * 192 + kt * 32 + lg * 8);

    float4 b2v[2];
    b2v[0] = *(const float4*)&b2[cbase + lg * 4];
    b2v[1] = *(const float4*)&b2[cbase + 16 + lg * 4];

    float st_s[8], st_q[8];
    #pragma unroll
    for (int i = 0; i < 8; ++i) { st_s[i] = 0.f; st_q[i] = 0.f; }

    #pragma unroll
    for (int nt = 0; nt < 4; ++nt) {
        short8 bf[6];
        #pragma unroll
        for (int kt = 0; kt < 6; ++kt)
            bf[kt] = *(const short8*)&A_lds[nt * 16 + lr][kt * 32 + lg * 8];
        #pragma unroll
        for (int ct = 0; ct < 2; ++ct) {
            f32x4 acc = {0.f, 0.f, 0.f, 0.f};
            #pragma unroll
            for (int kt = 0; kt < 6; ++kt)
                acc = __builtin_amdgcn_mfma_f32_16x16x32_bf16(af[ct * 6 + kt], bf[kt], acc, 0, 0, 0);
            const int c0 = cbase + ct * 16 + lg * 4;
            const size_t row = (size_t)pair0 * 16 + nt * 16 + lr;
            union { __hip_bfloat16 h[4]; uint2 u2; } pk;
            const float4 bb = b2v[ct];
            float vb[4] = {bb.x, bb.y, bb.z, bb.w};
            #pragma unroll
            for (int cc = 0; cc < 4; ++cc) {
                float v = acc[cc] + vb[cc];
                st_s[ct * 4 + cc] += v;
                st_q[ct * 4 + cc] = fmaf(v, v, st_q[ct * 4 + cc]);
                pk.h[cc] = __float2bfloat16(v);
            }
            *(uint2*)(z2 + row * CC + c0) = pk.u2;
        }
    }
    #pragma unroll
    for (int i = 0; i < 8; ++i) {
        float s = st_s[i], q = st_q[i];
        #pragma unroll
        for (int m = 1; m < 16; m <<= 1) { s += __shfl_xor(s, m); q += __shfl_xor(q, m); }
        if (lr == 0) {
            int ct = i >> 2, cc = i & 3;
            int c = cbase + ct * 16 + lg * 4 + cc;
            atomicAdd(&bn2slots[(bid & 63) * 256 + c * 2], s);
            atomicAdd(&bn2slots[(bid & 63) * 256 + c * 2 + 1], q);
        }
    }
}

__global__ void k_bn2(const float* __restrict__ slots, const float* __restrict__ g2,
                      const float* __restrict__ be2, float* __restrict__ par) {
    __shared__ float red[256];
    int tid = threadIdx.x;
    float v = 0.f;
    for (int s = 0; s < 64; ++s) v += slots[s * 256 + tid];
    red[tid] = v;
    __syncthreads();
    if (tid < 128) {
        const float invN = 1.0f / (float)NROWS;
        float mean = red[2 * tid] * invN;
        float var = red[2 * tid + 1] * invN - mean * mean;
        float sc = g2[tid] * rsqrtf(var + EPSV);
        par[160 + tid] = sc;
        par[288 + tid] = be2[tid] - mean * sc;
    }
}

// Epilogue: BN2+ReLU, weight by w_diag, sum over K, residual, transpose to (B,C,N).
__global__ __launch_bounds__(256) void k_out(const __hip_bfloat16* __restrict__ z2, const float* __restrict__ zw_raw,
                                             const float* __restrict__ par, const float* __restrict__ F_E,
                                             float* __restrict__ out) {
    __shared__ float wd[32][16];
    __shared__ float outs[32][129];
    const int tid = threadIdx.x;
    const int b = blockIdx.x >> 7;
    const int r0 = (blockIdx.x & 127) * 32;
    const int rowbase = (b * RN + r0) * 16;
    for (int o = tid; o < 512; o += 256) {
        int rr = o >> 4, k = o & 15;
        wd[rr][k] = fmaxf(fmaf(zw_raw[rowbase + o], par[128 + k], par[144 + k]), 0.f);
    }
    __syncthreads();
    const int c0 = (tid & 63) * 2;
    const int rh = tid >> 6;
    const float sc0 = par[160 + c0], sh0 = par[288 + c0];
    const float sc1 = par[160 + c0 + 1], sh1 = par[288 + c0 + 1];
    for (int rr = rh; rr < 32; rr += 4) {
        float a0 = 0.f, a1 = 0.f;
        const __hip_bfloat16* zp = z2 + ((size_t)rowbase + rr * 16) * CC + c0;
        #pragma unroll
        for (int k = 0; k < 16; ++k) {
            unsigned int uu = *(const unsigned int*)(zp + k * CC);
            float z0 = __uint_as_float(uu << 16);
            float z1 = __uint_as_float(uu & 0xFFFF0000u);
            float w = wd[rr][k];
            a0 += fmaxf(fmaf(z0, sc0, sh0), 0.f) * w;
            a1 += fmaxf(fmaf(z1, sc1, sh1), 0.f) * w;
        }
        outs[rr][c0] = a0; outs[rr][c0 + 1] = a1;
    }
    __syncthreads();
    for (int o = tid; o < 4096; o += 256) {
        int c = o >> 5, rr = o & 31;
        size_t oi = ((size_t)b * CC + c) * RN + r0 + rr;
        out[oi] = outs[rr][c] + F_E[oi];
    }
}

extern "C" void kernel_launch(void* const* d_in, const int* in_sizes, int n_in,
                              void* d_out, int out_size, void* d_ws, size_t ws_size,
                              hipStream_t stream) {
    const float* F_E = (const float*)d_in[0];
    const float* Qp  = (const float*)d_in[1];
    const float* W1  = (const float*)d_in[2];
    const float* b1  = (const float*)d_in[3];
    const float* g1  = (const float*)d_in[4];
    const float* be1 = (const float*)d_in[5];
    const float* W2  = (const float*)d_in[6];
    const float* b2  = (const float*)d_in[7];
    const float* g2  = (const float*)d_in[8];
    const float* be2 = (const float*)d_in[9];
    const float* Ww  = (const float*)d_in[10];
    const float* bw  = (const float*)d_in[11];
    const float* gw  = (const float*)d_in[12];
    const float* bew = (const float*)d_in[13];
    float* out = (float*)d_out;
    float* wsf = (float*)d_ws;

    float* bn2slots   = wsf;
    float* statslots  = wsf + 16384;
    float* par        = wsf + 17152;
    ushort* W2b       = (ushort*)(wsf + 17664);
    float4* qpack     = (float4*)(wsf + 32768);
    int* idxb         = (int*)(wsf + 98304);
    float* zw_raw     = wsf + 360448;
    ushort* ftb       = (ushort*)(wsf + 622592);
    __hip_bfloat16* z2 = (__hip_bfloat16*)(wsf + 1671168);

    hipMemsetAsync(d_ws, 0, 17152 * sizeof(float), stream);
    k_prep<<<160, 256, 0, stream>>>(Qp, qpack, W2, W2b);
    k_transpose<<<2048, 256, 0, stream>>>(F_E, ftb);
    k_knn<<<4096, 256, 0, stream>>>(qpack, idxb, zw_raw, statslots, Ww, bw);
    k_bn1<<<1, 128, 0, stream>>>(statslots, W1, b1, g1, be1, Ww, bw, gw, bew, par);
    k_main<<<4096, 256, 0, stream>>>(ftb, idxb, qpack, W1, b1, W2b, b2, par, bn2slots, z2);
    k_bn2<<<1, 256, 0, stream>>>(bn2slots, g2, be2, par);
    k_out<<<512, 256, 0, stream>>>(z2, zw_raw, par, F_E, out);
}